// Round 5
// baseline (950.684 us; speedup 1.0000x reference)
//
#include <hip/hip_runtime.h>
#include <math.h>

#define N_NODES 50000
#define N_EDGES 800000
#define D 128
#define E_FEAT 16
#define NLAYERS 3
#define BN_EPS 1e-5f
#define INV_SQRT2 0.70710678118654752f

// Branchless erf (Abramowitz-Stegun 7.1.26, |err| <= 1.5e-7) via hw rcp/exp2.
__device__ __forceinline__ float gelu_fast(float v) {
    const float u = v * INV_SQRT2;
    const float a = __builtin_fabsf(u);
    const float t = __builtin_amdgcn_rcpf(__builtin_fmaf(0.3275911f, a, 1.0f));
    float p = __builtin_fmaf(1.061405429f, t, -1.453152027f);
    p = __builtin_fmaf(p, t, 1.421413741f);
    p = __builtin_fmaf(p, t, -0.284496736f);
    p = __builtin_fmaf(p, t, 0.254829592f);
    p = p * t;
    const float e = __builtin_amdgcn_exp2f(-1.4426950408889634f * a * a);
    const float erf_a = __builtin_fmaf(-p, e, 1.0f);
    const float erf_u = __builtin_copysignf(erf_a, u);
    return 0.5f * v * (1.0f + erf_u);
}

// ---------------- CSR build ----------------
__global__ __launch_bounds__(256) void count_kernel(const int* __restrict__ dst,
                                                    int* __restrict__ counts) {
    int e = blockIdx.x * 256 + threadIdx.x;
    if (e < N_EDGES) atomicAdd(&counts[dst[e]], 1);
}

#define NSCAN_BLOCKS 196
__global__ __launch_bounds__(256) void scan1_kernel(const int* __restrict__ counts,
                                                    int* __restrict__ offsets,
                                                    int* __restrict__ bsum) {
    __shared__ int wsum[4];
    __shared__ int wexcl[4];
    const int t = threadIdx.x, lane = t & 63, wid = t >> 6;
    const int idx = blockIdx.x * 256 + t;
    int v = (idx < N_NODES) ? counts[idx] : 0;
    int incl = v;
    #pragma unroll
    for (int off = 1; off < 64; off <<= 1) {
        int u = __shfl_up(incl, off, 64);
        if (lane >= off) incl += u;
    }
    if (lane == 63) wsum[wid] = incl;
    __syncthreads();
    if (t == 0) {
        int r = 0;
        #pragma unroll
        for (int g = 0; g < 4; ++g) { wexcl[g] = r; r += wsum[g]; }
        bsum[blockIdx.x] = r;
    }
    __syncthreads();
    if (idx < N_NODES) offsets[idx] = wexcl[wid] + (incl - v);
}

__global__ __launch_bounds__(256) void scan2_kernel(const int* __restrict__ bsum,
                                                    int* __restrict__ bbase,
                                                    int* __restrict__ offsets) {
    __shared__ int wsum[4];
    __shared__ int wexcl[4];
    const int t = threadIdx.x, lane = t & 63, wid = t >> 6;
    int v = (t < NSCAN_BLOCKS) ? bsum[t] : 0;
    int incl = v;
    #pragma unroll
    for (int off = 1; off < 64; off <<= 1) {
        int u = __shfl_up(incl, off, 64);
        if (lane >= off) incl += u;
    }
    if (lane == 63) wsum[wid] = incl;
    __syncthreads();
    if (t == 0) {
        int r = 0;
        #pragma unroll
        for (int g = 0; g < 4; ++g) { wexcl[g] = r; r += wsum[g]; }
        offsets[N_NODES] = r;
    }
    __syncthreads();
    if (t < NSCAN_BLOCKS) bbase[t] = wexcl[wid] + (incl - v);
}

__global__ __launch_bounds__(256) void scan3_kernel(int* __restrict__ offsets,
                                                    const int* __restrict__ bbase,
                                                    int* __restrict__ cursor) {
    const int idx = blockIdx.x * 256 + threadIdx.x;
    if (idx < N_NODES) {
        const int o = offsets[idx] + bbase[blockIdx.x];
        offsets[idx] = o;
        cursor[idx] = o;
    }
}

// scatter: only the 4-byte eid (random 4B writes are cheap; 64B random writes were not)
__global__ __launch_bounds__(256) void scatter_kernel(const int* __restrict__ dst,
                                                      int* __restrict__ cursor,
                                                      int* __restrict__ sorted_eid) {
    int e = blockIdx.x * 256 + threadIdx.x;
    if (e < N_EDGES) {
        int p = atomicAdd(&cursor[dst[e]], 1);
        sorted_eid[p] = e;
    }
}

// permute: gather-based (random READS cache in L2/LLC; writes fully coalesced)
__global__ __launch_bounds__(256) void permute_kernel(
    const int* __restrict__ sorted_eid,
    const int* __restrict__ src,
    const float* __restrict__ ew,
    const float* __restrict__ ea,
    int* __restrict__ sorted_src,
    float* __restrict__ sorted_ew,
    float* __restrict__ sorted_ea)
{
    int p = blockIdx.x * 256 + threadIdx.x;
    if (p < N_EDGES) {
        const int e = sorted_eid[p];
        sorted_src[p] = src[e];
        sorted_ew[p]  = ew[e];
        const float4* s4 = (const float4*)(ea + (size_t)e * E_FEAT);
        float4* d4 = (float4*)(sorted_ea + (size_t)p * E_FEAT);
        d4[0] = s4[0]; d4[1] = s4[1]; d4[2] = s4[2]; d4[3] = s4[3];
    }
}

// ---------------- aggregation: grid-stride waves, 2-stage software pipeline ----------------
// pre[n] = (1+eps)*x[n] + sum_{e: dst=n} gelu(x[src_e] + ea_e@We + be) * ew_e
#define AGG_BLOCKS 2048
#define AGG_WAVES (AGG_BLOCKS * 4)

__global__ __launch_bounds__(256) void aggregate_kernel(
    const float* __restrict__ x,
    const int* __restrict__ sorted_src,
    const float* __restrict__ sorted_ew,
    const float* __restrict__ sorted_ea,
    const int* __restrict__ offsets,
    const float* __restrict__ We,          // 16 x 128
    const float* __restrict__ be,          // 128
    const float* __restrict__ eps_p,
    float* __restrict__ pre)               // N x 128
{
    const int t = threadIdx.x;
    const int lane = t & 63;
    const int gw = blockIdx.x * 4 + (t >> 6);   // global wave id, 8192 waves
    const int c0 = lane * 2;

    float2 wreg[E_FEAT];
    #pragma unroll
    for (int k = 0; k < E_FEAT; ++k)
        wreg[k] = *(const float2*)&We[k * D + c0];
    const float2 bev = *(const float2*)&be[c0];
    const float e1 = 1.0f + *eps_p;

    for (int node = gw; node < N_NODES; node += AGG_WAVES) {
        const int start = __builtin_amdgcn_readfirstlane(offsets[node]);
        const int end   = __builtin_amdgcn_readfirstlane(offsets[node + 1]);
        const int cnt   = end - start;

        float a0 = 0.0f, a1 = 0.0f;

        // ---- pipeline prologue (clamped, branchless indices) ----
        const int p0 = min(start, N_EDGES - 1);
        const int p1 = min(start + 1, N_EDGES - 1);
        // stage A: meta + x-row for edge start; sB: src for edge start+1
        int   sB = __builtin_amdgcn_readfirstlane(sorted_src[p1]);
        const int sA0 = __builtin_amdgcn_readfirstlane(sorted_src[p0]);
        float2 xv = *(const float2*)&x[(size_t)sA0 * D + c0];
        float wA = sorted_ew[p0];
        float eaA[E_FEAT];
        #pragma unroll
        for (int k = 0; k < E_FEAT; ++k) eaA[k] = sorted_ea[(size_t)p0 * E_FEAT + k];

        for (int i = 0; i < cnt; ++i) {
            const int p   = start + i;
            const int pn1 = min(p + 1, N_EDGES - 1);
            const int pn2 = min(p + 2, N_EDGES - 1);

            // issue next-stage loads first (no intra-iteration dependencies)
            const int sC = __builtin_amdgcn_readfirstlane(sorted_src[pn2]);
            const float2 xn = *(const float2*)&x[(size_t)sB * D + c0];
            const float wB = sorted_ew[pn1];
            float eaB[E_FEAT];
            #pragma unroll
            for (int k = 0; k < E_FEAT; ++k) eaB[k] = sorted_ea[(size_t)pn1 * E_FEAT + k];

            // compute with stage-A values (all resident since previous iteration)
            float m0 = bev.x, m1 = bev.y;
            #pragma unroll
            for (int k = 0; k < E_FEAT; ++k) {
                m0 = __builtin_fmaf(eaA[k], wreg[k].x, m0);
                m1 = __builtin_fmaf(eaA[k], wreg[k].y, m1);
            }
            a0 = __builtin_fmaf(gelu_fast(xv.x + m0), wA, a0);
            a1 = __builtin_fmaf(gelu_fast(xv.y + m1), wA, a1);

            // rotate stages
            sB = sC; xv = xn; wA = wB;
            #pragma unroll
            for (int k = 0; k < E_FEAT; ++k) eaA[k] = eaB[k];
        }

        const float2 xnode = *(const float2*)&x[(size_t)node * D + c0];
        float2 o;
        o.x = e1 * xnode.x + a0;
        o.y = e1 * xnode.y + a1;
        *(float2*)&pre[(size_t)node * D + c0] = o;
    }
}

// ---------------- fused MLP: H = gelu(pre@W1+b1)@W2+b2, plus col stats ----------------
#define GM 64
#define LDA 132

__global__ __launch_bounds__(256) void mlp_fused_kernel(
    const float* __restrict__ pre,
    const float* __restrict__ W1,
    const float* __restrict__ b1,
    const float* __restrict__ W2,
    const float* __restrict__ b2,
    float* __restrict__ H,
    float* __restrict__ colsum,
    float* __restrict__ colsumsq)
{
    __shared__ float sA[GM][LDA];
    const int t = threadIdx.x;
    const int row0 = blockIdx.x * GM;

    for (int i = t; i < GM * (D / 4); i += 256) {
        const int r  = i / (D / 4);
        const int cc = (i % (D / 4)) * 4;
        const int gr = row0 + r;
        float4 v;
        if (gr < N_NODES) v = *(const float4*)&pre[(size_t)gr * D + cc];
        else { v.x = v.y = v.z = v.w = 0.0f; }
        *(float4*)&sA[r][cc] = v;
    }
    __syncthreads();

    const int cg = t & 31;
    const int rg = t >> 5;
    const int c0 = cg * 4;
    const int r0 = rg * 8;
    float acc[8][4];

    #pragma unroll
    for (int r = 0; r < 8; ++r)
        #pragma unroll
        for (int cc = 0; cc < 4; ++cc) acc[r][cc] = 0.0f;

    for (int k = 0; k < D; k += 4) {
        const float4 w0 = *(const float4*)&W1[(size_t)(k + 0) * D + c0];
        const float4 w1 = *(const float4*)&W1[(size_t)(k + 1) * D + c0];
        const float4 w2 = *(const float4*)&W1[(size_t)(k + 2) * D + c0];
        const float4 w3 = *(const float4*)&W1[(size_t)(k + 3) * D + c0];
        #pragma unroll
        for (int r = 0; r < 8; ++r) {
            const float4 a = *(const float4*)&sA[r0 + r][k];
            acc[r][0] += a.x * w0.x + a.y * w1.x + a.z * w2.x + a.w * w3.x;
            acc[r][1] += a.x * w0.y + a.y * w1.y + a.z * w2.y + a.w * w3.y;
            acc[r][2] += a.x * w0.z + a.y * w1.z + a.z * w2.z + a.w * w3.z;
            acc[r][3] += a.x * w0.w + a.y * w1.w + a.z * w2.w + a.w * w3.w;
        }
    }
    __syncthreads();

    {
        const float4 bb = *(const float4*)&b1[c0];
        #pragma unroll
        for (int r = 0; r < 8; ++r) {
            float4 o;
            o.x = gelu_fast(acc[r][0] + bb.x);
            o.y = gelu_fast(acc[r][1] + bb.y);
            o.z = gelu_fast(acc[r][2] + bb.z);
            o.w = gelu_fast(acc[r][3] + bb.w);
            *(float4*)&sA[r0 + r][c0] = o;
        }
    }
    __syncthreads();

    #pragma unroll
    for (int r = 0; r < 8; ++r)
        #pragma unroll
        for (int cc = 0; cc < 4; ++cc) acc[r][cc] = 0.0f;

    for (int k = 0; k < D; k += 4) {
        const float4 w0 = *(const float4*)&W2[(size_t)(k + 0) * D + c0];
        const float4 w1 = *(const float4*)&W2[(size_t)(k + 1) * D + c0];
        const float4 w2 = *(const float4*)&W2[(size_t)(k + 2) * D + c0];
        const float4 w3 = *(const float4*)&W2[(size_t)(k + 3) * D + c0];
        #pragma unroll
        for (int r = 0; r < 8; ++r) {
            const float4 a = *(const float4*)&sA[r0 + r][k];
            acc[r][0] += a.x * w0.x + a.y * w1.x + a.z * w2.x + a.w * w3.x;
            acc[r][1] += a.x * w0.y + a.y * w1.y + a.z * w2.y + a.w * w3.y;
            acc[r][2] += a.x * w0.z + a.y * w1.z + a.z * w2.z + a.w * w3.z;
            acc[r][3] += a.x * w0.w + a.y * w1.w + a.z * w2.w + a.w * w3.w;
        }
    }

    const float4 bb = *(const float4*)&b2[c0];
    float s[4] = {0.f, 0.f, 0.f, 0.f};
    float q[4] = {0.f, 0.f, 0.f, 0.f};
    #pragma unroll
    for (int r = 0; r < 8; ++r) {
        const int gr = row0 + r0 + r;
        if (gr < N_NODES) {
            float4 o;
            o.x = acc[r][0] + bb.x; o.y = acc[r][1] + bb.y;
            o.z = acc[r][2] + bb.z; o.w = acc[r][3] + bb.w;
            *(float4*)&H[(size_t)gr * D + c0] = o;
            s[0] += o.x; s[1] += o.y; s[2] += o.z; s[3] += o.w;
            q[0] += o.x * o.x; q[1] += o.y * o.y; q[2] += o.z * o.z; q[3] += o.w * o.w;
        }
    }

    __syncthreads();
    #pragma unroll
    for (int cc = 0; cc < 4; ++cc) {
        sA[rg][c0 + cc]     = s[cc];
        sA[8 + rg][c0 + cc] = q[cc];
    }
    __syncthreads();
    if (t < D) {
        float ss = 0.f, qq = 0.f;
        #pragma unroll
        for (int gg = 0; gg < 8; ++gg) { ss += sA[gg][t]; qq += sA[8 + gg][t]; }
        atomicAdd(&colsum[t], ss);
        atomicAdd(&colsumsq[t], qq);
    }
}

// ---------------- BN apply + gelu + residual ----------------
__global__ __launch_bounds__(256) void bn_apply_kernel(
    const float* __restrict__ H,
    const float* __restrict__ colsum,
    const float* __restrict__ colsumsq,
    const float* __restrict__ gamma,
    const float* __restrict__ beta,
    const float* __restrict__ x_in,
    float* __restrict__ x_out)
{
    const int idx = blockIdx.x * 256 + threadIdx.x;
    const int c0 = (idx & 31) * 4;
    const float invN = 1.0f / (float)N_NODES;

    const float4 s  = *(const float4*)&colsum[c0];
    const float4 q  = *(const float4*)&colsumsq[c0];
    const float4 g  = *(const float4*)&gamma[c0];
    const float4 bt = *(const float4*)&beta[c0];
    const float4 h  = *(const float4*)&H[(size_t)idx * 4];
    const float4 xv = *(const float4*)&x_in[(size_t)idx * 4];

    float4 o;
    {
        float mu = s.x * invN, var = q.x * invN - mu * mu;
        float hn = (h.x - mu) * rsqrtf(var + BN_EPS) * g.x + bt.x;
        o.x = (xv.x + gelu_fast(hn)) * INV_SQRT2;
    }
    {
        float mu = s.y * invN, var = q.y * invN - mu * mu;
        float hn = (h.y - mu) * rsqrtf(var + BN_EPS) * g.y + bt.y;
        o.y = (xv.y + gelu_fast(hn)) * INV_SQRT2;
    }
    {
        float mu = s.z * invN, var = q.z * invN - mu * mu;
        float hn = (h.z - mu) * rsqrtf(var + BN_EPS) * g.z + bt.z;
        o.z = (xv.z + gelu_fast(hn)) * INV_SQRT2;
    }
    {
        float mu = s.w * invN, var = q.w * invN - mu * mu;
        float hn = (h.w - mu) * rsqrtf(var + BN_EPS) * g.w + bt.w;
        o.w = (xv.w + gelu_fast(hn)) * INV_SQRT2;
    }
    *(float4*)&x_out[(size_t)idx * 4] = o;
}

extern "C" void kernel_launch(void* const* d_in, const int* in_sizes, int n_in,
                              void* d_out, int out_size, void* d_ws, size_t ws_size,
                              hipStream_t stream) {
    const float* x_in  = (const float*)d_in[0];
    const int*   ei    = (const int*)d_in[1];
    const float* ea    = (const float*)d_in[2];
    const float* ew    = (const float*)d_in[3];
    const float* We    = (const float*)d_in[4];
    const float* be    = (const float*)d_in[5];
    const float* W1    = (const float*)d_in[6];
    const float* b1    = (const float*)d_in[7];
    const float* W2    = (const float*)d_in[8];
    const float* b2    = (const float*)d_in[9];
    const float* eps   = (const float*)d_in[10];
    const float* gamma = (const float*)d_in[11];
    const float* beta  = (const float*)d_in[12];

    const int* src = ei;
    const int* dst = ei + N_EDGES;

    float* xcur = (float*)d_out;

    // ws layout:
    // [counts 50000][colsum_all 384f][colsumsq_all 384f][cursor 50000]
    // [offsets 50004][bsum 256][bbase 256][sorted_eid 800000]
    // [sorted_src 800000][sorted_ew 800000f][sorted_ea 12.8Mf][preH 6.4Mf]
    int*   counts       = (int*)d_ws;
    float* colsum_all   = (float*)(counts + N_NODES);
    float* colsumsq_all = colsum_all + NLAYERS * D;
    int*   cursor       = (int*)(colsumsq_all + NLAYERS * D);
    int*   offsets      = cursor + N_NODES;
    int*   bsum         = offsets + N_NODES + 4;
    int*   bbase        = bsum + 256;
    int*   sorted_eid   = bbase + 256;
    int*   sorted_src   = sorted_eid + N_EDGES;
    float* sorted_ew    = (float*)(sorted_src + N_EDGES);
    float* sorted_ea    = sorted_ew + N_EDGES;     // 16B-aligned by construction
    float* preH         = sorted_ea + (size_t)N_EDGES * E_FEAT;

    hipMemsetAsync(counts, 0, sizeof(int) * (N_NODES + 2 * NLAYERS * D), stream);
    count_kernel<<<(N_EDGES + 255) / 256, 256, 0, stream>>>(dst, counts);
    scan1_kernel<<<NSCAN_BLOCKS, 256, 0, stream>>>(counts, offsets, bsum);
    scan2_kernel<<<1, 256, 0, stream>>>(bsum, bbase, offsets);
    scan3_kernel<<<NSCAN_BLOCKS, 256, 0, stream>>>(offsets, bbase, cursor);
    scatter_kernel<<<(N_EDGES + 255) / 256, 256, 0, stream>>>(dst, cursor, sorted_eid);
    permute_kernel<<<(N_EDGES + 255) / 256, 256, 0, stream>>>(
        sorted_eid, src, ew, ea, sorted_src, sorted_ew, sorted_ea);

    const int mlp_blocks = (N_NODES + GM - 1) / GM;
    const int bn_blocks  = (N_NODES * D / 4) / 256;

    for (int i = 0; i < NLAYERS; ++i) {
        const float* xl = (i == 0) ? x_in : xcur;
        aggregate_kernel<<<AGG_BLOCKS, 256, 0, stream>>>(
            xl, sorted_src, sorted_ew, sorted_ea, offsets, We, be, eps + i, preH);
        mlp_fused_kernel<<<mlp_blocks, 256, 0, stream>>>(
            preH, W1 + (size_t)i * D * D, b1 + (size_t)i * D,
            W2 + (size_t)i * D * D, b2 + (size_t)i * D,
            preH, colsum_all + i * D, colsumsq_all + i * D);
        bn_apply_kernel<<<bn_blocks, 256, 0, stream>>>(
            preH, colsum_all + i * D, colsumsq_all + i * D,
            gamma + (size_t)i * D, beta + (size_t)i * D, xl, xcur);
    }
}

// Round 6
// 689.999 us; speedup vs baseline: 1.3778x; 1.3778x over previous
//
#include <hip/hip_runtime.h>
#include <math.h>

#define N_NODES 50000
#define N_EDGES 800000
#define D 128
#define E_FEAT 16
#define NLAYERS 3
#define BN_EPS 1e-5f
#define INV_SQRT2 0.70710678118654752f

typedef __attribute__((ext_vector_type(8))) short short8;
typedef __attribute__((ext_vector_type(4))) float f32x4;

// Branchless erf (Abramowitz-Stegun 7.1.26, |err| <= 1.5e-7) via hw rcp/exp2.
__device__ __forceinline__ float gelu_fast(float v) {
    const float u = v * INV_SQRT2;
    const float a = __builtin_fabsf(u);
    const float t = __builtin_amdgcn_rcpf(__builtin_fmaf(0.3275911f, a, 1.0f));
    float p = __builtin_fmaf(1.061405429f, t, -1.453152027f);
    p = __builtin_fmaf(p, t, 1.421413741f);
    p = __builtin_fmaf(p, t, -0.284496736f);
    p = __builtin_fmaf(p, t, 0.254829592f);
    p = p * t;
    const float e = __builtin_amdgcn_exp2f(-1.4426950408889634f * a * a);
    const float erf_a = __builtin_fmaf(-p, e, 1.0f);
    const float erf_u = __builtin_copysignf(erf_a, u);
    return 0.5f * v * (1.0f + erf_u);
}

// fp32 -> bf16 bits, round-to-nearest-even
__device__ __forceinline__ unsigned short f2bf(float f) {
    unsigned u = __float_as_uint(f);
    unsigned r = (u + 0x7FFFu + ((u >> 16) & 1u)) >> 16;
    return (unsigned short)r;
}

// ---------------- CSR build ----------------
__global__ __launch_bounds__(256) void count_kernel(const int* __restrict__ dst,
                                                    int* __restrict__ counts) {
    int e = blockIdx.x * 256 + threadIdx.x;
    if (e < N_EDGES) atomicAdd(&counts[dst[e]], 1);
}

#define NSCAN_BLOCKS 196
__global__ __launch_bounds__(256) void scan1_kernel(const int* __restrict__ counts,
                                                    int* __restrict__ offsets,
                                                    int* __restrict__ bsum) {
    __shared__ int wsum[4];
    __shared__ int wexcl[4];
    const int t = threadIdx.x, lane = t & 63, wid = t >> 6;
    const int idx = blockIdx.x * 256 + t;
    int v = (idx < N_NODES) ? counts[idx] : 0;
    int incl = v;
    #pragma unroll
    for (int off = 1; off < 64; off <<= 1) {
        int u = __shfl_up(incl, off, 64);
        if (lane >= off) incl += u;
    }
    if (lane == 63) wsum[wid] = incl;
    __syncthreads();
    if (t == 0) {
        int r = 0;
        #pragma unroll
        for (int g = 0; g < 4; ++g) { wexcl[g] = r; r += wsum[g]; }
        bsum[blockIdx.x] = r;
    }
    __syncthreads();
    if (idx < N_NODES) offsets[idx] = wexcl[wid] + (incl - v);
}

__global__ __launch_bounds__(256) void scan2_kernel(const int* __restrict__ bsum,
                                                    int* __restrict__ bbase,
                                                    int* __restrict__ offsets) {
    __shared__ int wsum[4];
    __shared__ int wexcl[4];
    const int t = threadIdx.x, lane = t & 63, wid = t >> 6;
    int v = (t < NSCAN_BLOCKS) ? bsum[t] : 0;
    int incl = v;
    #pragma unroll
    for (int off = 1; off < 64; off <<= 1) {
        int u = __shfl_up(incl, off, 64);
        if (lane >= off) incl += u;
    }
    if (lane == 63) wsum[wid] = incl;
    __syncthreads();
    if (t == 0) {
        int r = 0;
        #pragma unroll
        for (int g = 0; g < 4; ++g) { wexcl[g] = r; r += wsum[g]; }
        offsets[N_NODES] = r;
    }
    __syncthreads();
    if (t < NSCAN_BLOCKS) bbase[t] = wexcl[wid] + (incl - v);
}

__global__ __launch_bounds__(256) void scan3_kernel(int* __restrict__ offsets,
                                                    const int* __restrict__ bbase,
                                                    int* __restrict__ cursor) {
    const int idx = blockIdx.x * 256 + threadIdx.x;
    if (idx < N_NODES) {
        const int o = offsets[idx] + bbase[blockIdx.x];
        offsets[idx] = o;
        cursor[idx] = o;
    }
}

__global__ __launch_bounds__(256) void scatter_kernel(const int* __restrict__ dst,
                                                      int* __restrict__ cursor,
                                                      int* __restrict__ sorted_eid) {
    int e = blockIdx.x * 256 + threadIdx.x;
    if (e < N_EDGES) {
        int p = atomicAdd(&cursor[dst[e]], 1);
        sorted_eid[p] = e;
    }
}

__global__ __launch_bounds__(256) void permute_kernel(
    const int* __restrict__ sorted_eid,
    const int* __restrict__ src,
    const float* __restrict__ ew,
    const float* __restrict__ ea,
    int* __restrict__ sorted_src,
    float* __restrict__ sorted_ew,
    float* __restrict__ sorted_ea)
{
    int p = blockIdx.x * 256 + threadIdx.x;
    if (p < N_EDGES) {
        const int e = sorted_eid[p];
        sorted_src[p] = src[e];
        sorted_ew[p]  = ew[e];
        const float4* s4 = (const float4*)(ea + (size_t)e * E_FEAT);
        float4* d4 = (float4*)(sorted_ea + (size_t)p * E_FEAT);
        d4[0] = s4[0]; d4[1] = s4[1]; d4[2] = s4[2]; d4[3] = s4[3];
    }
}

// pack W (K x N, row-major) into MFMA B-fragment order, bf16:
// Wp[(((m*8+ct)*4+kt)*64+lane)*8 + j] = bf16(W[kt*32+(lane>>4)*8+j][ct*16+(lane&15)])
__global__ __launch_bounds__(256) void pack_kernel(const float* __restrict__ W1,
                                                   const float* __restrict__ W2,
                                                   unsigned short* __restrict__ Wp) {
    const int idx = blockIdx.x * 256 + threadIdx.x;   // 6*2048 = 12288 items
    if (idx >= 6 * 2048) return;
    const int m    = idx >> 11;
    const int rem  = idx & 2047;
    const int ct   = rem >> 8;
    const int rem2 = rem & 255;
    const int kt   = rem2 >> 6;
    const int lane = rem2 & 63;
    const float* Wsrc = (m < 3) ? (W1 + (size_t)m * D * D)
                                : (W2 + (size_t)(m - 3) * D * D);
    const int k0  = kt * 32 + (lane >> 4) * 8;
    const int col = ct * 16 + (lane & 15);
    unsigned short o[8];
    #pragma unroll
    for (int j = 0; j < 8; ++j) o[j] = f2bf(Wsrc[(size_t)(k0 + j) * D + col]);
    unsigned short* d = Wp + (size_t)idx * 8;
    #pragma unroll
    for (int j = 0; j < 8; ++j) d[j] = o[j];
}

// ---------------- aggregation: one wave per node, unroll-2 edge pairs ----------------
// pre[n] = (1+eps)*x[n] + sum_{e: dst=n} gelu(x[src_e] + ea_e@We + be) * ew_e
__global__ __launch_bounds__(256, 4) void aggregate_kernel(
    const float* __restrict__ x,
    const int* __restrict__ sorted_src,
    const float* __restrict__ sorted_ew,
    const float* __restrict__ sorted_ea,
    const int* __restrict__ offsets,
    const float* __restrict__ We,          // 16 x 128
    const float* __restrict__ be,          // 128
    const float* __restrict__ eps_p,
    float* __restrict__ pre)               // N x 128
{
    const int t = threadIdx.x;
    const int lane = t & 63;
    const int node = blockIdx.x * 4 + (t >> 6);   // 12500 blocks
    const int c0 = lane * 2;

    // launch_bounds(256,4): VGPR cap 128 so wreg stays register-resident
    float2 wreg[E_FEAT];
    #pragma unroll
    for (int k = 0; k < E_FEAT; ++k)
        wreg[k] = *(const float2*)&We[k * D + c0];
    const float2 bev = *(const float2*)&be[c0];
    const float e1 = 1.0f + *eps_p;

    const int start = __builtin_amdgcn_readfirstlane(offsets[node]);
    const int end   = __builtin_amdgcn_readfirstlane(offsets[node + 1]);

    float a0 = 0.0f, a1 = 0.0f;
    int p = start;
    for (; p + 2 <= end; p += 2) {
        // independent loads for BOTH edges issue before any compute
        const int s0 = __builtin_amdgcn_readfirstlane(sorted_src[p]);
        const int s1 = __builtin_amdgcn_readfirstlane(sorted_src[p + 1]);
        const float2 x0 = *(const float2*)&x[(size_t)s0 * D + c0];
        const float2 x1 = *(const float2*)&x[(size_t)s1 * D + c0];
        const float w0 = sorted_ew[p];
        const float w1 = sorted_ew[p + 1];
        const float* __restrict__ ea0 = sorted_ea + (size_t)p * E_FEAT;
        const float* __restrict__ ea1 = ea0 + E_FEAT;

        float m00 = bev.x, m01 = bev.y, m10 = bev.x, m11 = bev.y;
        #pragma unroll
        for (int k = 0; k < E_FEAT; ++k) {
            const float e0k = ea0[k];
            m00 = __builtin_fmaf(e0k, wreg[k].x, m00);
            m01 = __builtin_fmaf(e0k, wreg[k].y, m01);
        }
        #pragma unroll
        for (int k = 0; k < E_FEAT; ++k) {
            const float e1k = ea1[k];
            m10 = __builtin_fmaf(e1k, wreg[k].x, m10);
            m11 = __builtin_fmaf(e1k, wreg[k].y, m11);
        }
        a0 = __builtin_fmaf(gelu_fast(x0.x + m00), w0, a0);
        a1 = __builtin_fmaf(gelu_fast(x0.y + m01), w0, a1);
        a0 = __builtin_fmaf(gelu_fast(x1.x + m10), w1, a0);
        a1 = __builtin_fmaf(gelu_fast(x1.y + m11), w1, a1);
    }
    if (p < end) {   // odd tail
        const int s0 = __builtin_amdgcn_readfirstlane(sorted_src[p]);
        const float2 x0 = *(const float2*)&x[(size_t)s0 * D + c0];
        const float w0 = sorted_ew[p];
        const float* __restrict__ ea0 = sorted_ea + (size_t)p * E_FEAT;
        float m00 = bev.x, m01 = bev.y;
        #pragma unroll
        for (int k = 0; k < E_FEAT; ++k) {
            const float e0k = ea0[k];
            m00 = __builtin_fmaf(e0k, wreg[k].x, m00);
            m01 = __builtin_fmaf(e0k, wreg[k].y, m01);
        }
        a0 = __builtin_fmaf(gelu_fast(x0.x + m00), w0, a0);
        a1 = __builtin_fmaf(gelu_fast(x0.y + m01), w0, a1);
    }

    const float2 xnode = *(const float2*)&x[(size_t)node * D + c0];
    float2 o;
    o.x = e1 * xnode.x + a0;
    o.y = e1 * xnode.y + a1;
    *(float2*)&pre[(size_t)node * D + c0] = o;
}

// ---------------- fused MLP via bf16 MFMA ----------------
// H = gelu(pre@W1+b1)@W2+b2  (+ column sum/sumsq for BN)
// Per block: 64 rows x 128 cols. Each wave owns a PRIVATE 16x128 slab ->
// no inter-wave barriers between GEMM1 / gelu-writeback / GEMM2.
#define GM 64
#define LDB 136   // ushort leading dim: row stride 272 B -> 2-way (free) LDS pattern

__global__ __launch_bounds__(256, 4) void mlp_fused_kernel(
    const float* __restrict__ pre,
    const unsigned short* __restrict__ Wp1,   // packed B-frag bf16
    const float* __restrict__ b1,
    const unsigned short* __restrict__ Wp2,
    const float* __restrict__ b2,
    float* __restrict__ H,
    float* __restrict__ colsum,
    float* __restrict__ colsumsq)
{
    __shared__ __align__(16) unsigned short sAb[GM * LDB];  // 17408 B
    __shared__ float sred[2][4][D];                         // 4096 B
    const int t = threadIdx.x;
    const int row0 = blockIdx.x * GM;

    // stage pre tile as bf16
    for (int i = t; i < GM * (D / 4); i += 256) {
        const int r  = i / (D / 4);
        const int cc = (i % (D / 4)) * 4;
        const int gr = row0 + r;
        float4 v;
        if (gr < N_NODES) v = *(const float4*)&pre[(size_t)gr * D + cc];
        else { v.x = v.y = v.z = v.w = 0.0f; }
        ushort4 h;
        h.x = f2bf(v.x); h.y = f2bf(v.y); h.z = f2bf(v.z); h.w = f2bf(v.w);
        *(ushort4*)&sAb[r * LDB + cc] = h;
    }
    __syncthreads();

    const int wave = t >> 6, lane = t & 63;
    const int m0   = wave * 16;        // this wave's row slab
    const int mrow = lane & 15;
    const int q    = lane >> 4;
    const int colb = lane & 15;

    // A fragments (A[m=lane&15][k=q*8+j]) for all 4 k-tiles
    short8 a[4];
    #pragma unroll
    for (int kt = 0; kt < 4; ++kt)
        a[kt] = *(const short8*)&sAb[(m0 + mrow) * LDB + kt * 32 + q * 8];

    // ---- GEMM 1 ----
    f32x4 acc[8];
    #pragma unroll
    for (int ct = 0; ct < 8; ++ct) acc[ct] = (f32x4){0.f, 0.f, 0.f, 0.f};
    #pragma unroll
    for (int ct = 0; ct < 8; ++ct) {
        #pragma unroll
        for (int kt = 0; kt < 4; ++kt) {
            const short8 b = *(const short8*)&Wp1[((size_t)(ct * 4 + kt) * 64 + lane) * 8];
            acc[ct] = __builtin_amdgcn_mfma_f32_16x16x32_bf16(a[kt], b, acc[ct], 0, 0, 0);
        }
    }

    // gelu(acc + b1) -> back into own slab as bf16 (C/D: row=q*4+r, col=lane&15)
    #pragma unroll
    for (int ct = 0; ct < 8; ++ct) {
        const float bb = b1[ct * 16 + colb];
        #pragma unroll
        for (int r = 0; r < 4; ++r) {
            const float o = gelu_fast(acc[ct][r] + bb);
            sAb[(m0 + q * 4 + r) * LDB + ct * 16 + colb] = f2bf(o);
        }
    }
    // same-wave LDS RAW: compiler inserts lgkmcnt wait; no barrier needed

    // ---- GEMM 2 ----
    #pragma unroll
    for (int kt = 0; kt < 4; ++kt)
        a[kt] = *(const short8*)&sAb[(m0 + mrow) * LDB + kt * 32 + q * 8];
    #pragma unroll
    for (int ct = 0; ct < 8; ++ct) acc[ct] = (f32x4){0.f, 0.f, 0.f, 0.f};
    #pragma unroll
    for (int ct = 0; ct < 8; ++ct) {
        #pragma unroll
        for (int kt = 0; kt < 4; ++kt) {
            const short8 b = *(const short8*)&Wp2[((size_t)(ct * 4 + kt) * 64 + lane) * 8];
            acc[ct] = __builtin_amdgcn_mfma_f32_16x16x32_bf16(a[kt], b, acc[ct], 0, 0, 0);
        }
    }

    // epilogue: + b2, store H, column stats
    #pragma unroll
    for (int ct = 0; ct < 8; ++ct) {
        const float bb = b2[ct * 16 + colb];
        float ssum = 0.f, qsum = 0.f;
        #pragma unroll
        for (int r = 0; r < 4; ++r) {
            const int grow = row0 + m0 + q * 4 + r;
            const float o = acc[ct][r] + bb;
            if (grow < N_NODES) {
                H[(size_t)grow * D + ct * 16 + colb] = o;
                ssum += o;
                qsum += o * o;
            }
        }
        ssum += __shfl_xor(ssum, 16, 64);
        ssum += __shfl_xor(ssum, 32, 64);
        qsum += __shfl_xor(qsum, 16, 64);
        qsum += __shfl_xor(qsum, 32, 64);
        if (q == 0) {
            sred[0][wave][ct * 16 + colb] = ssum;
            sred[1][wave][ct * 16 + colb] = qsum;
        }
    }
    __syncthreads();
    if (t < D) {
        const float ss = sred[0][0][t] + sred[0][1][t] + sred[0][2][t] + sred[0][3][t];
        const float qq = sred[1][0][t] + sred[1][1][t] + sred[1][2][t] + sred[1][3][t];
        atomicAdd(&colsum[t], ss);
        atomicAdd(&colsumsq[t], qq);
    }
}

// ---------------- BN apply + gelu + residual ----------------
__global__ __launch_bounds__(256) void bn_apply_kernel(
    const float* __restrict__ H,
    const float* __restrict__ colsum,
    const float* __restrict__ colsumsq,
    const float* __restrict__ gamma,
    const float* __restrict__ beta,
    const float* __restrict__ x_in,
    float* __restrict__ x_out)
{
    const int idx = blockIdx.x * 256 + threadIdx.x;
    const int c0 = (idx & 31) * 4;
    const float invN = 1.0f / (float)N_NODES;

    const float4 s  = *(const float4*)&colsum[c0];
    const float4 q  = *(const float4*)&colsumsq[c0];
    const float4 g  = *(const float4*)&gamma[c0];
    const float4 bt = *(const float4*)&beta[c0];
    const float4 h  = *(const float4*)&H[(size_t)idx * 4];
    const float4 xv = *(const float4*)&x_in[(size_t)idx * 4];

    float4 o;
    {
        float mu = s.x * invN, var = q.x * invN - mu * mu;
        float hn = (h.x - mu) * rsqrtf(var + BN_EPS) * g.x + bt.x;
        o.x = (xv.x + gelu_fast(hn)) * INV_SQRT2;
    }
    {
        float mu = s.y * invN, var = q.y * invN - mu * mu;
        float hn = (h.y - mu) * rsqrtf(var + BN_EPS) * g.y + bt.y;
        o.y = (xv.y + gelu_fast(hn)) * INV_SQRT2;
    }
    {
        float mu = s.z * invN, var = q.z * invN - mu * mu;
        float hn = (h.z - mu) * rsqrtf(var + BN_EPS) * g.z + bt.z;
        o.z = (xv.z + gelu_fast(hn)) * INV_SQRT2;
    }
    {
        float mu = s.w * invN, var = q.w * invN - mu * mu;
        float hn = (h.w - mu) * rsqrtf(var + BN_EPS) * g.w + bt.w;
        o.w = (xv.w + gelu_fast(hn)) * INV_SQRT2;
    }
    *(float4*)&x_out[(size_t)idx * 4] = o;
}

extern "C" void kernel_launch(void* const* d_in, const int* in_sizes, int n_in,
                              void* d_out, int out_size, void* d_ws, size_t ws_size,
                              hipStream_t stream) {
    const float* x_in  = (const float*)d_in[0];
    const int*   ei    = (const int*)d_in[1];
    const float* ea    = (const float*)d_in[2];
    const float* ew    = (const float*)d_in[3];
    const float* We    = (const float*)d_in[4];
    const float* be    = (const float*)d_in[5];
    const float* W1    = (const float*)d_in[6];
    const float* b1    = (const float*)d_in[7];
    const float* W2    = (const float*)d_in[8];
    const float* b2    = (const float*)d_in[9];
    const float* eps   = (const float*)d_in[10];
    const float* gamma = (const float*)d_in[11];
    const float* beta  = (const float*)d_in[12];

    const int* src = ei;
    const int* dst = ei + N_EDGES;

    float* xcur = (float*)d_out;

    // ws layout:
    // [counts 50000][colsum_all 384f][colsumsq_all 384f][cursor 50000]
    // [offsets 50004][bsum 256][bbase 256][sorted_eid 800000]
    // [sorted_src 800000][sorted_ew 800000f][sorted_ea 12.8Mf]
    // [Wpack 98304 ushort (49152 dwords)][preH 6.4Mf]
    int*   counts       = (int*)d_ws;
    float* colsum_all   = (float*)(counts + N_NODES);
    float* colsumsq_all = colsum_all + NLAYERS * D;
    int*   cursor       = (int*)(colsumsq_all + NLAYERS * D);
    int*   offsets      = cursor + N_NODES;
    int*   bsum         = offsets + N_NODES + 4;
    int*   bbase        = bsum + 256;
    int*   sorted_eid   = bbase + 256;
    int*   sorted_src   = sorted_eid + N_EDGES;
    float* sorted_ew    = (float*)(sorted_src + N_EDGES);
    float* sorted_ea    = sorted_ew + N_EDGES;
    unsigned short* Wpack = (unsigned short*)(sorted_ea + (size_t)N_EDGES * E_FEAT);
    float* preH         = (float*)(Wpack + 6 * 2048 * 8);

    hipMemsetAsync(counts, 0, sizeof(int) * (N_NODES + 2 * NLAYERS * D), stream);
    count_kernel<<<(N_EDGES + 255) / 256, 256, 0, stream>>>(dst, counts);
    scan1_kernel<<<NSCAN_BLOCKS, 256, 0, stream>>>(counts, offsets, bsum);
    scan2_kernel<<<1, 256, 0, stream>>>(bsum, bbase, offsets);
    scan3_kernel<<<NSCAN_BLOCKS, 256, 0, stream>>>(offsets, bbase, cursor);
    scatter_kernel<<<(N_EDGES + 255) / 256, 256, 0, stream>>>(dst, cursor, sorted_eid);
    permute_kernel<<<(N_EDGES + 255) / 256, 256, 0, stream>>>(
        sorted_eid, src, ew, ea, sorted_src, sorted_ew, sorted_ea);
    pack_kernel<<<48, 256, 0, stream>>>(W1, W2, Wpack);

    const int mlp_blocks = (N_NODES + GM - 1) / GM;   // 782
    const int bn_blocks  = (N_NODES * D / 4) / 256;   // 6250
    const int agg_blocks = N_NODES / 4;               // 12500

    for (int i = 0; i < NLAYERS; ++i) {
        const float* xl = (i == 0) ? x_in : xcur;
        aggregate_kernel<<<agg_blocks, 256, 0, stream>>>(
            xl, sorted_src, sorted_ew, sorted_ea, offsets, We, be, eps + i, preH);
        mlp_fused_kernel<<<mlp_blocks, 256, 0, stream>>>(
            preH, Wpack + (size_t)i * 16384, b1 + (size_t)i * D,
            Wpack + (size_t)(3 + i) * 16384, b2 + (size_t)i * D,
            preH, colsum_all + i * D, colsumsq_all + i * D);
        bn_apply_kernel<<<bn_blocks, 256, 0, stream>>>(
            preH, colsum_all + i * D, colsumsq_all + i * D,
            gamma + (size_t)i * D, beta + (size_t)i * D, xl, xcur);
    }
}